// Round 1
// baseline (3148.163 us; speedup 1.0000x reference)
//
#include <hip/hip_runtime.h>
#include <math.h>

#define TS 64
#define KT 16

// Generic batched GEMM: C = alpha * A*B(^T) [+ mask] [+ resid]
// Batch z decomposed as z1 = z/zdiv, z2 = z%zdiv with separate offsets, so
// one kernel covers per-head column-blocked layouts and (b,h) batching.
__global__ __launch_bounds__(256) void gemm_k(
    const float* __restrict__ Ag, const float* __restrict__ Bg, float* __restrict__ Cg,
    int lda, int ldb, int ldc, int K,
    int zdiv,
    long aB1, long aB2, long bB1, long bB2, long cB1, long cB2,
    int transB, float alpha,
    const float* __restrict__ mask, int maskLd,
    const float* __restrict__ resid, int ldr)
{
    const int z  = blockIdx.z;
    const int z1 = z / zdiv, z2 = z % zdiv;
    const float* A = Ag + z1 * aB1 + z2 * aB2;
    const float* B = Bg + z1 * bB1 + z2 * bB2;
    float*       C = Cg + z1 * cB1 + z2 * cB2;

    // +4 pad: rows stay 16B-aligned for b128 reads, breaks pow2 bank stride
    __shared__ float As[KT][TS + 4];
    __shared__ float Bs[KT][TS + 4];

    const int tid = threadIdx.x;
    const int m0 = blockIdx.y * TS;
    const int n0 = blockIdx.x * TS;
    const int tm = tid >> 4;          // 0..15
    const int tn = tid & 15;          // 0..15

    const int l_m  = tid >> 2;        // 0..63 (A / B^T row)
    const int l_k  = (tid & 3) << 2;  // 0,4,8,12
    const int b_r  = tid >> 4;        // 0..15 (B NN row)
    const int b_c  = (tid & 15) << 2; // 0..60

    float acc[4][4] = {};

    for (int k0 = 0; k0 < K; k0 += KT) {
        float4 a4 = *reinterpret_cast<const float4*>(A + (long)(m0 + l_m) * lda + k0 + l_k);
        As[l_k + 0][l_m] = a4.x; As[l_k + 1][l_m] = a4.y;
        As[l_k + 2][l_m] = a4.z; As[l_k + 3][l_m] = a4.w;
        if (!transB) {
            float4 b4 = *reinterpret_cast<const float4*>(B + (long)(k0 + b_r) * ldb + n0 + b_c);
            Bs[b_r][b_c + 0] = b4.x; Bs[b_r][b_c + 1] = b4.y;
            Bs[b_r][b_c + 2] = b4.z; Bs[b_r][b_c + 3] = b4.w;
        } else {
            float4 b4 = *reinterpret_cast<const float4*>(B + (long)(n0 + l_m) * ldb + k0 + l_k);
            Bs[l_k + 0][l_m] = b4.x; Bs[l_k + 1][l_m] = b4.y;
            Bs[l_k + 2][l_m] = b4.z; Bs[l_k + 3][l_m] = b4.w;
        }
        __syncthreads();
        #pragma unroll
        for (int kk = 0; kk < KT; ++kk) {
            float av[4], bv[4];
            #pragma unroll
            for (int i = 0; i < 4; ++i) av[i] = As[kk][tm * 4 + i];
            #pragma unroll
            for (int j = 0; j < 4; ++j) bv[j] = Bs[kk][tn * 4 + j];
            #pragma unroll
            for (int i = 0; i < 4; ++i)
                #pragma unroll
                for (int j = 0; j < 4; ++j)
                    acc[i][j] = fmaf(av[i], bv[j], acc[i][j]);
        }
        __syncthreads();
    }

    #pragma unroll
    for (int i = 0; i < 4; ++i) {
        const int m = m0 + tm * 4 + i;
        #pragma unroll
        for (int j = 0; j < 4; ++j) {
            const int n = n0 + tn * 4 + j;
            float v = acc[i][j] * alpha;
            if (mask)  v += mask[(long)m * maskLd + n];
            if (resid) v += resid[(long)m * ldr + n];
            C[(long)m * ldc + n] = v;
        }
    }
}

// In-place row softmax over rows of 512; one wave per row, 4 rows per block.
__global__ __launch_bounds__(256) void softmax_k(float* __restrict__ att)
{
    const int lane = threadIdx.x & 63;
    const int wave = threadIdx.x >> 6;
    const long row = (long)blockIdx.x * 4 + wave;
    float* p = att + row * 512;

    float v[8], mx = -INFINITY;
    #pragma unroll
    for (int i = 0; i < 8; ++i) { v[i] = p[lane + i * 64]; mx = fmaxf(mx, v[i]); }
    #pragma unroll
    for (int off = 32; off > 0; off >>= 1) mx = fmaxf(mx, __shfl_xor(mx, off));
    float s = 0.f;
    #pragma unroll
    for (int i = 0; i < 8; ++i) { v[i] = __expf(v[i] - mx); s += v[i]; }
    #pragma unroll
    for (int off = 32; off > 0; off >>= 1) s += __shfl_xor(s, off);
    const float inv = 1.0f / s;
    #pragma unroll
    for (int i = 0; i < 8; ++i) p[lane + i * 64] = v[i] * inv;
}

extern "C" void kernel_launch(void* const* d_in, const int* in_sizes, int n_in,
                              void* d_out, int out_size, void* d_ws, size_t ws_size,
                              hipStream_t stream)
{
    const float* tokens = (const float*)d_in[0];
    const float* mask   = (const float*)d_in[1];
    const float* embedW = (const float*)d_in[2];
    const float* unembW = (const float*)d_in[3];
    const float* wq     = (const float*)d_in[4];
    const float* wk     = (const float*)d_in[5];
    const float* wv     = (const float*)d_in[6];
    const float* wo     = (const float*)d_in[7];

    const int B = 8, S = 512, V = 256, D = 1024, P = 128, H = 8, L = 4;
    const int BS = B * S;                 // 4096
    const float rs = 0.08838834764831845f; // 1/sqrt(128)

    float* out       = (float*)d_out;
    float* logits_o  = out;                                  // [B,S,V]
    float* atts_o    = out + (long)B * S * V;                // [L,B,H,S,S]
    float* streams_o = atts_o + (long)L * B * H * S * S;     // [L+1,B,S,D]

    // ws: Q, K, V each [BS, H*P] fp32 (16 MB); comb reuses Q after QK^T.
    float* Q    = (float*)d_ws;
    float* Kb   = Q  + (long)BS * H * P;
    float* Vb   = Kb + (long)BS * H * P;
    float* comb = Q;

    dim3 blk(256);

    // stream0 = tokens @ embedW  -> streams[0]
    gemm_k<<<dim3(D / TS, BS / TS, 1), blk, 0, stream>>>(
        tokens, embedW, streams_o,
        V, D, D, V, 1, 0, 0, 0, 0, 0, 0,
        0, 1.0f, nullptr, 0, nullptr, 0);

    for (int l = 0; l < L; ++l) {
        float* st  = streams_o + (long)l * BS * D;
        float* stn = st + (long)BS * D;
        const float* wql = wq + (long)l * H * D * P;
        const float* wkl = wk + (long)l * H * D * P;
        const float* wvl = wv + (long)l * H * D * P;
        const float* wol = wo + (long)l * H * P * D;
        float* attl = atts_o + (long)l * B * H * S * S;

        // Q/K/V: per-head [4096,1024]x[1024,128] -> [BS, h*128 + p]
        gemm_k<<<dim3(P / TS, BS / TS, H), blk, 0, stream>>>(
            st, wql, Q, D, P, H * P, D, 1,
            0, 0, (long)D * P, 0, (long)P, 0,
            0, 1.0f, nullptr, 0, nullptr, 0);
        gemm_k<<<dim3(P / TS, BS / TS, H), blk, 0, stream>>>(
            st, wkl, Kb, D, P, H * P, D, 1,
            0, 0, (long)D * P, 0, (long)P, 0,
            0, 1.0f, nullptr, 0, nullptr, 0);
        gemm_k<<<dim3(P / TS, BS / TS, H), blk, 0, stream>>>(
            st, wvl, Vb, D, P, H * P, D, 1,
            0, 0, (long)D * P, 0, (long)P, 0,
            0, 1.0f, nullptr, 0, nullptr, 0);

        // logits[b,h] = Q K^T / sqrt(P) + mask -> atts[l] (scratch for softmax)
        gemm_k<<<dim3(S / TS, S / TS, B * H), blk, 0, stream>>>(
            Q, Kb, attl,
            H * P, H * P, S, P, H,
            (long)S * H * P, (long)P,
            (long)S * H * P, (long)P,
            (long)H * S * S, (long)S * S,
            1, rs, mask, S, nullptr, 0);

        // softmax rows in-place: B*H*S = 32768 rows, 4 per block
        softmax_k<<<dim3(B * H * S / 4), blk, 0, stream>>>(attl);

        // comb[b,h] = att @ V  -> [BS, h*128 + p] (reuses Q buffer)
        gemm_k<<<dim3(P / TS, S / TS, B * H), blk, 0, stream>>>(
            attl, Vb, comb,
            S, H * P, H * P, S, H,
            (long)H * S * S, (long)S * S,
            (long)S * H * P, (long)P,
            (long)S * H * P, (long)P,
            0, 1.0f, nullptr, 0, nullptr, 0);

        // stream_{l+1} = stream_l + comb @ wo[l]  ([4096,1024]x[1024,1024])
        gemm_k<<<dim3(D / TS, BS / TS, 1), blk, 0, stream>>>(
            comb, wol, stn,
            H * P, D, D, H * P, 1, 0, 0, 0, 0, 0, 0,
            0, 1.0f, nullptr, 0, st, D);
    }

    // logits = stream_L @ unembW
    gemm_k<<<dim3(V / TS, BS / TS, 1), blk, 0, stream>>>(
        streams_o + (long)L * BS * D, unembW, logits_o,
        D, V, V, D, 1, 0, 0, 0, 0, 0, 0,
        0, 1.0f, nullptr, 0, nullptr, 0);
}

// Round 2
// 1326.996 us; speedup vs baseline: 2.3724x; 2.3724x over previous
//
#include <hip/hip_runtime.h>
#include <math.h>

typedef __bf16 bf16x8 __attribute__((ext_vector_type(8)));
typedef float  f32x4  __attribute__((ext_vector_type(4)));

// ---------------- transpose + fp32->bf16 convert: out[c][r] = in[r][c] ----------------
// block (32,8); grid (C/32, R/32, Z)
__global__ __launch_bounds__(256) void transpose_cvt(
    const float* __restrict__ in, __bf16* __restrict__ out,
    int C, int outLd, long inZ, long outZ)
{
    __shared__ float t[32][33];
    const int z = blockIdx.z;
    in  += (long)z * inZ;
    out += (long)z * outZ;
    const int c0 = blockIdx.x * 32, r0 = blockIdx.y * 32;
    const int tx = threadIdx.x, ty = threadIdx.y;
    #pragma unroll
    for (int i = 0; i < 32; i += 8)
        t[ty + i][tx] = in[(long)(r0 + ty + i) * C + c0 + tx];
    __syncthreads();
    #pragma unroll
    for (int i = 0; i < 32; i += 8)
        out[(long)(c0 + ty + i) * outLd + r0 + tx] = (__bf16)t[tx][ty + i];
}

// ---------------- batched MFMA GEMM: C = alpha*A*Bt^T [+mask] [+resid] ----------------
// A: [M,K] bf16 or fp32 (a_f32). Bt: [N,K] bf16. Tile 128x128, BK=32, 4 waves.
// Outputs: optional fp32 (outF) and/or bf16 (outB); vt!=null reroutes cols n>=2048
// to a [b,h,p,s] transposed store (QKV's V-section).
__global__ __launch_bounds__(256) void mfma_gemm(
    const void* __restrict__ Ag, const __bf16* __restrict__ Bg,
    int lda, int ldb, int K, int a_f32, int zdiv,
    long aB1, long aB2, long bB1, long bB2,
    float* __restrict__ outF, long fB1, long fB2, int ldf,
    __bf16* __restrict__ outB, long oB1, long oB2, int ldo,
    __bf16* __restrict__ vt,
    float alpha,
    const float* __restrict__ mask, int maskLd,
    const float* __restrict__ resid, int ldr)
{
    const int z = blockIdx.z, z1 = z / zdiv, z2 = z % zdiv;
    const int m0 = blockIdx.y * 128, n0 = blockIdx.x * 128;

    __shared__ __bf16 As[128][40];   // [m][k], +8 pad keeps 16B align, breaks pow2 stride
    __shared__ __bf16 Bs[128][40];   // [n][k]

    const __bf16* B   = Bg + z1 * bB1 + z2 * bB2;
    const float*  A32 = (const float*)Ag;
    const __bf16* A16 = (const __bf16*)Ag;
    const long aOff = z1 * aB1 + z2 * aB2;

    const int t  = threadIdx.x;
    const int sr = t >> 2, sc = (t & 3) * 8;        // staging: row 0..63, kcol {0,8,16,24}
    const int lane = t & 63, w = t >> 6;
    const int wm = (w >> 1) * 64, wn = (w & 1) * 64; // 2x2 wave grid, 64x64 per wave
    const int r = lane & 15, q = lane >> 4;

    f32x4 acc[4][4];
    #pragma unroll
    for (int i = 0; i < 4; ++i)
        #pragma unroll
        for (int j = 0; j < 4; ++j)
            acc[i][j] = f32x4{0.f, 0.f, 0.f, 0.f};

    for (int k0 = 0; k0 < K; k0 += 32) {
        #pragma unroll
        for (int p = 0; p < 2; ++p) {
            const int row = sr + p * 64;
            if (a_f32) {
                const float* s = A32 + aOff + (long)(m0 + row) * lda + k0 + sc;
                float4 f0 = *(const float4*)s;
                float4 f1 = *(const float4*)(s + 4);
                __bf16* d = &As[row][sc];
                d[0]=(__bf16)f0.x; d[1]=(__bf16)f0.y; d[2]=(__bf16)f0.z; d[3]=(__bf16)f0.w;
                d[4]=(__bf16)f1.x; d[5]=(__bf16)f1.y; d[6]=(__bf16)f1.z; d[7]=(__bf16)f1.w;
            } else {
                *(bf16x8*)&As[row][sc] =
                    *(const bf16x8*)(A16 + aOff + (long)(m0 + row) * lda + k0 + sc);
            }
            *(bf16x8*)&Bs[row][sc] =
                *(const bf16x8*)(B + (long)(n0 + row) * ldb + k0 + sc);
        }
        __syncthreads();
        bf16x8 af[4], bv[4];
        #pragma unroll
        for (int i = 0; i < 4; ++i) af[i] = *(const bf16x8*)&As[wm + i * 16 + r][q * 8];
        #pragma unroll
        for (int j = 0; j < 4; ++j) bv[j] = *(const bf16x8*)&Bs[wn + j * 16 + r][q * 8];
        #pragma unroll
        for (int i = 0; i < 4; ++i)
            #pragma unroll
            for (int j = 0; j < 4; ++j)
                acc[i][j] = __builtin_amdgcn_mfma_f32_16x16x32_bf16(af[i], bv[j], acc[i][j], 0, 0, 0);
        __syncthreads();
    }

    const long fOff = z1 * fB1 + z2 * fB2;
    const long oOff = z1 * oB1 + z2 * oB2;
    #pragma unroll
    for (int i = 0; i < 4; ++i) {
        #pragma unroll
        for (int j = 0; j < 4; ++j) {
            #pragma unroll
            for (int g = 0; g < 4; ++g) {
                const int m = m0 + wm + i * 16 + q * 4 + g;
                const int n = n0 + wn + j * 16 + r;
                float v = acc[i][j][g] * alpha;
                if (mask)  v += mask[(long)m * maskLd + n];
                if (resid) v += resid[(long)m * ldr + n];
                if (outF)  outF[fOff + (long)m * ldf + n] = v;
                if (outB) {
                    if (vt && n >= 2048) {
                        const int p = n - 2048, h = p >> 7, pp = p & 127;
                        const int b = m >> 9, s = m & 511;
                        vt[(((long)(b * 8 + h)) * 128 + pp) * 512 + s] = (__bf16)v;
                    } else {
                        outB[oOff + (long)m * ldo + n] = (__bf16)v;
                    }
                }
            }
        }
    }
}

// ---------------- in-place row softmax, rows of 512; 1 wave/row, 4 rows/block --------
__global__ __launch_bounds__(256) void softmax_k(float* __restrict__ att)
{
    const int lane = threadIdx.x & 63;
    const int wave = threadIdx.x >> 6;
    const long row = (long)blockIdx.x * 4 + wave;
    float* p = att + row * 512;

    float v[8], mx = -INFINITY;
    #pragma unroll
    for (int i = 0; i < 8; ++i) { v[i] = p[lane + i * 64]; mx = fmaxf(mx, v[i]); }
    #pragma unroll
    for (int off = 32; off > 0; off >>= 1) mx = fmaxf(mx, __shfl_xor(mx, off));
    float s = 0.f;
    #pragma unroll
    for (int i = 0; i < 8; ++i) { v[i] = __expf(v[i] - mx); s += v[i]; }
    #pragma unroll
    for (int off = 32; off > 0; off >>= 1) s += __shfl_xor(s, off);
    const float inv = 1.0f / s;
    #pragma unroll
    for (int i = 0; i < 8; ++i) p[lane + i * 64] = v[i] * inv;
}

extern "C" void kernel_launch(void* const* d_in, const int* in_sizes, int n_in,
                              void* d_out, int out_size, void* d_ws, size_t ws_size,
                              hipStream_t stream)
{
    const float* tokens = (const float*)d_in[0];
    const float* mask   = (const float*)d_in[1];
    const float* embedW = (const float*)d_in[2];
    const float* unembW = (const float*)d_in[3];
    const float* wq     = (const float*)d_in[4];
    const float* wk     = (const float*)d_in[5];
    const float* wv     = (const float*)d_in[6];
    const float* wo     = (const float*)d_in[7];

    const float rs = 0.08838834764831845f; // 1/sqrt(128)

    float* out       = (float*)d_out;
    float* logits_o  = out;                           // [8,512,256]
    float* atts_o    = out + 1048576L;                // [4,8,8,512,512]
    float* streams_o = atts_o + 67108864L;            // [5,8,512,1024]

    // ws (bf16 elements), ~43 MB total
    __bf16* embedWt   = (__bf16*)d_ws;                // [1024][256]
    __bf16* unembWt   = embedWt + 262144;             // [256][1024]
    __bf16* Wt        = unembWt + 262144;             // [3072][1024] (q|k|v, per layer)
    __bf16* Wot       = Wt + 3145728;                 // [1024][1024] (per layer)
    __bf16* stream_bf = Wot + 1048576;                // [4096][1024]
    __bf16* QKV       = stream_bf + 4194304;          // [4096][2048] = q|k sections
    __bf16* Vt        = QKV + 8388608;                // [8][8][128][512]
    __bf16* comb      = QKV;                          // alias: q/k dead after QK^T

    const dim3 T(32, 8), G1(256);

    // weight transposes (fp32 -> bf16, [N][K] form)
    transpose_cvt<<<dim3(32, 8, 1), T, 0, stream>>>(embedW, embedWt, 1024, 256, 0, 0);
    transpose_cvt<<<dim3(8, 32, 1), T, 0, stream>>>(unembW, unembWt, 256, 1024, 0, 0);

    // embed: [4096,256] x [256,1024] -> streams[0] fp32 + stream_bf
    mfma_gemm<<<dim3(8, 32, 1), G1, 0, stream>>>(
        tokens, embedWt, 256, 256, 256, 1, 1, 0, 0, 0, 0,
        streams_o, 0, 0, 1024,
        stream_bf, 0, 0, 1024,
        nullptr, 1.0f, nullptr, 0, nullptr, 0);

    for (int l = 0; l < 4; ++l) {
        float* attl = atts_o + (long)l * 16777216;
        float* st   = streams_o + (long)l * 4194304;
        float* stn  = st + 4194304;

        transpose_cvt<<<dim3(4, 32, 8), T, 0, stream>>>(wq + (long)l * 1048576, Wt,           128, 1024, 131072, 131072);
        transpose_cvt<<<dim3(4, 32, 8), T, 0, stream>>>(wk + (long)l * 1048576, Wt + 1048576, 128, 1024, 131072, 131072);
        transpose_cvt<<<dim3(4, 32, 8), T, 0, stream>>>(wv + (long)l * 1048576, Wt + 2097152, 128, 1024, 131072, 131072);
        transpose_cvt<<<dim3(32, 32, 1), T, 0, stream>>>(wo + (long)l * 1048576, Wot, 1024, 1024, 0, 0);

        // QKV: [4096,1024] x [1024,3072]; q,k -> QKV[.,0:2048], v -> Vt transposed
        mfma_gemm<<<dim3(24, 32, 1), G1, 0, stream>>>(
            stream_bf, Wt, 1024, 1024, 1024, 0, 1, 0, 0, 0, 0,
            nullptr, 0, 0, 0,
            QKV, 0, 0, 2048,
            Vt, 1.0f, nullptr, 0, nullptr, 0);

        // logits = Q K^T / sqrt(P) + mask -> atts[l] (fp32)
        mfma_gemm<<<dim3(4, 4, 64), G1, 0, stream>>>(
            QKV, QKV + 1024, 2048, 2048, 128, 0, 8,
            1048576, 128, 1048576, 128,
            attl, 2097152, 262144, 512,
            nullptr, 0, 0, 0,
            nullptr, rs, mask, 512, nullptr, 0);

        softmax_k<<<dim3(8192), G1, 0, stream>>>(attl);

        // comb = att @ V : A fp32 atts (converted in staging), B = Vt
        mfma_gemm<<<dim3(1, 4, 64), G1, 0, stream>>>(
            attl, Vt, 512, 512, 512, 1, 8,
            2097152, 262144, 524288, 65536,
            nullptr, 0, 0, 0,
            comb, 524288, 128, 1024,
            nullptr, 1.0f, nullptr, 0, nullptr, 0);

        // stream_{l+1} = stream_l + comb @ wo
        mfma_gemm<<<dim3(8, 32, 1), G1, 0, stream>>>(
            comb, Wot, 1024, 1024, 1024, 0, 1, 0, 0, 0, 0,
            stn, 0, 0, 1024,
            stream_bf, 0, 0, 1024,
            nullptr, 1.0f, nullptr, 0, st, 1024);
    }

    // logits = stream_L @ unembW
    mfma_gemm<<<dim3(2, 32, 1), G1, 0, stream>>>(
        stream_bf, unembWt, 1024, 1024, 1024, 0, 1, 0, 0, 0, 0,
        logits_o, 0, 0, 256,
        nullptr, 0, 0, 0,
        nullptr, 1.0f, nullptr, 0, nullptr, 0);
}

// Round 3
// 1049.184 us; speedup vs baseline: 3.0006x; 1.2648x over previous
//
#include <hip/hip_runtime.h>
#include <math.h>

typedef __bf16 bf16x8 __attribute__((ext_vector_type(8)));
typedef float  f32x4  __attribute__((ext_vector_type(4)));

#define GLOAD16(g, l) __builtin_amdgcn_global_load_lds( \
    (const __attribute__((address_space(1))) void*)(g), \
    (__attribute__((address_space(3))) void*)(l), 16, 0, 0)

// ---------------- fp32 -> bf16 convert ----------------
__global__ __launch_bounds__(256) void cvt_bf16(const float* __restrict__ in,
                                                __bf16* __restrict__ out)
{
    const int i = (blockIdx.x * 256 + threadIdx.x) * 4;
    float4 f = *(const float4*)(in + i);
    out[i + 0] = (__bf16)f.x; out[i + 1] = (__bf16)f.y;
    out[i + 2] = (__bf16)f.z; out[i + 3] = (__bf16)f.w;
}

// ---------------- transpose + fp32->bf16: out[c][r] = in[r][c] ----------------
__global__ __launch_bounds__(256) void transpose_cvt(
    const float* __restrict__ in, __bf16* __restrict__ out,
    int C, int outLd, long inZ, int zdiv, long outZ1, long outZ2)
{
    __shared__ float t[32][33];
    const int z = blockIdx.z, z1 = z / zdiv, z2 = z % zdiv;
    in  += (long)z * inZ;
    out += z1 * outZ1 + z2 * outZ2;
    const int c0 = blockIdx.x * 32, r0 = blockIdx.y * 32;
    const int tx = threadIdx.x, ty = threadIdx.y;
    #pragma unroll
    for (int i = 0; i < 32; i += 8)
        t[ty + i][tx] = in[(long)(r0 + ty + i) * C + c0 + tx];
    __syncthreads();
    #pragma unroll
    for (int i = 0; i < 32; i += 8)
        out[(long)(c0 + ty + i) * outLd + r0 + tx] = (__bf16)t[tx][ty + i];
}

// ---------------- m97-style MFMA GEMM: C = A * Bt^T [+resid] ----------------
// A [M,K] bf16, Bt [N,K] bf16. Tile 128x128, BK=32, 4 waves, global_load_lds.
__global__ __launch_bounds__(256) void mfma_gemm(
    const __bf16* __restrict__ A, const __bf16* __restrict__ Bt,
    int lda, int ldb, int K,
    float* __restrict__ outF, int ldf,
    __bf16* __restrict__ outB, int ldo,
    __bf16* __restrict__ vt,
    const float* __restrict__ resid, int ldr)
{
    __shared__ __bf16 As[128 * 32];   // [m][k] unpadded (global_load_lds layout)
    __shared__ __bf16 Bs[128 * 32];   // [n][k]

    const int m0 = blockIdx.y * 128, n0 = blockIdx.x * 128;
    const int t = threadIdx.x, w = t >> 6, ln = t & 63;
    const int r = ln & 15, q = ln >> 4;
    const int wm = (w >> 1) * 64, wn = (w & 1) * 64;

    f32x4 acc[4][4];
    #pragma unroll
    for (int i = 0; i < 4; ++i)
        #pragma unroll
        for (int j = 0; j < 4; ++j)
            acc[i][j] = f32x4{0.f, 0.f, 0.f, 0.f};

    const int srow = ln >> 2, scol = (ln & 3) * 8; // within 16-row chunk

    for (int k0 = 0; k0 < K; k0 += 32) {
        #pragma unroll
        for (int c = 0; c < 2; ++c) {
            const int ch = w + c * 4;               // 8 chunks of 16 rows
            const __bf16* ga = A  + (long)(m0 + ch * 16 + srow) * lda + k0 + scol;
            GLOAD16(ga, &As[ch * 512]);
            const __bf16* gb = Bt + (long)(n0 + ch * 16 + srow) * ldb + k0 + scol;
            GLOAD16(gb, &Bs[ch * 512]);
        }
        __syncthreads();
        bf16x8 af[4], bv[4];
        #pragma unroll
        for (int i = 0; i < 4; ++i) af[i] = *(const bf16x8*)&As[(wm + i * 16 + r) * 32 + q * 8];
        #pragma unroll
        for (int i = 0; i < 4; ++i) bv[i] = *(const bf16x8*)&Bs[(wn + i * 16 + r) * 32 + q * 8];
        #pragma unroll
        for (int i = 0; i < 4; ++i)
            #pragma unroll
            for (int j = 0; j < 4; ++j)
                acc[i][j] = __builtin_amdgcn_mfma_f32_16x16x32_bf16(af[i], bv[j], acc[i][j], 0, 0, 0);
        __syncthreads();
    }

    #pragma unroll
    for (int i = 0; i < 4; ++i) {
        #pragma unroll
        for (int j = 0; j < 4; ++j) {
            #pragma unroll
            for (int g = 0; g < 4; ++g) {
                const int m = m0 + wm + i * 16 + q * 4 + g;
                const int n = n0 + wn + j * 16 + r;
                float v = acc[i][j][g];
                if (resid) v += resid[(long)m * ldr + n];
                if (outF)  outF[(long)m * ldf + n] = v;
                if (outB) {
                    if (vt && n >= 2048) {   // V section -> [b,h,p,s]
                        const int p = n - 2048, h = p >> 7, pp = p & 127;
                        const int b = m >> 9, s = m & 511;
                        vt[(((long)(b * 8 + h)) * 128 + pp) * 512 + s] = (__bf16)v;
                    } else {
                        outB[(long)m * ldo + n] = (__bf16)v;
                    }
                }
            }
        }
    }
}

// ---------------- fused causal attention (two-pass flash) ----------------
// QK: [4096][2048] bf16 (q | k, head-blocked). Vt: [64][128][512] bf16.
// atts: fp32 [64][512][512] (this layer). comb: [4096][1024] bf16.
__global__ __launch_bounds__(256) void flash_k(
    const __bf16* __restrict__ QK, const __bf16* __restrict__ Vt,
    float* __restrict__ atts, __bf16* __restrict__ comb)
{
    const int qb = blockIdx.x, bh = blockIdx.y;
    const int b = bh >> 3, h = bh & 7;
    const float rs = 0.08838834764831845f;

    __shared__ __bf16 Qs[128 * 136];
    __shared__ __bf16 Ks[128 * 136];
    __shared__ __bf16 Vs[128 * 136];
    __shared__ __bf16 Ps[128 * 136];

    const int t = threadIdx.x, w = t >> 6, ln = t & 63;
    const int r = ln & 15, q = ln >> 4;

    // stage Q rows [qb*128, +128)
    {
        const __bf16* src = QK + ((long)(b * 512 + qb * 128)) * 2048 + h * 128;
        for (int c = t; c < 2048; c += 256) {
            const int row = c >> 4, col = (c & 15) * 8;
            *(bf16x8*)&Qs[row * 136 + col] = *(const bf16x8*)(src + (long)row * 2048 + col);
        }
    }

    float m[2][4], l[2][4];
    #pragma unroll
    for (int i = 0; i < 2; ++i)
        #pragma unroll
        for (int g = 0; g < 4; ++g) { m[i][g] = -INFINITY; l[i][g] = 0.f; }

    // ---- pass 1: row max + denom ----
    for (int kt = 0; kt <= qb; ++kt) {
        __syncthreads();
        const __bf16* ksrc = QK + ((long)(b * 512 + kt * 128)) * 2048 + 1024 + h * 128;
        for (int c = t; c < 2048; c += 256) {
            const int row = c >> 4, col = (c & 15) * 8;
            *(bf16x8*)&Ks[row * 136 + col] = *(const bf16x8*)(ksrc + (long)row * 2048 + col);
        }
        __syncthreads();

        f32x4 S[2][8];
        #pragma unroll
        for (int i = 0; i < 2; ++i)
            #pragma unroll
            for (int nb = 0; nb < 8; ++nb) S[i][nb] = f32x4{0.f, 0.f, 0.f, 0.f};
        #pragma unroll
        for (int kp = 0; kp < 4; ++kp) {
            bf16x8 af[2], bv[8];
            #pragma unroll
            for (int i = 0; i < 2; ++i)
                af[i] = *(const bf16x8*)&Qs[(w * 32 + i * 16 + r) * 136 + kp * 32 + q * 8];
            #pragma unroll
            for (int nb = 0; nb < 8; ++nb)
                bv[nb] = *(const bf16x8*)&Ks[(nb * 16 + r) * 136 + kp * 32 + q * 8];
            #pragma unroll
            for (int i = 0; i < 2; ++i)
                #pragma unroll
                for (int nb = 0; nb < 8; ++nb)
                    S[i][nb] = __builtin_amdgcn_mfma_f32_16x16x32_bf16(af[i], bv[nb], S[i][nb], 0, 0, 0);
        }

        float tmax[2][4];
        #pragma unroll
        for (int i = 0; i < 2; ++i)
            #pragma unroll
            for (int g = 0; g < 4; ++g) tmax[i][g] = -INFINITY;
        #pragma unroll
        for (int i = 0; i < 2; ++i)
            #pragma unroll
            for (int nb = 0; nb < 8; ++nb)
                #pragma unroll
                for (int g = 0; g < 4; ++g) {
                    float v = S[i][nb][g] * rs;
                    if (kt == qb) {
                        const int qr = w * 32 + i * 16 + q * 4 + g, kc = nb * 16 + r;
                        if (kc > qr) v = -1e9f;
                    }
                    S[i][nb][g] = v;
                    tmax[i][g] = fmaxf(tmax[i][g], v);
                }
        #pragma unroll
        for (int i = 0; i < 2; ++i)
            #pragma unroll
            for (int g = 0; g < 4; ++g) {
                float tm = tmax[i][g];
                #pragma unroll
                for (int s = 1; s < 16; s <<= 1) tm = fmaxf(tm, __shfl_xor(tm, s));
                const float nm = fmaxf(m[i][g], tm);
                float ps = 0.f;
                #pragma unroll
                for (int nb = 0; nb < 8; ++nb) ps += __expf(S[i][nb][g] - nm);
                #pragma unroll
                for (int s = 1; s < 16; s <<= 1) ps += __shfl_xor(ps, s);
                l[i][g] = l[i][g] * __expf(m[i][g] - nm) + ps;
                m[i][g] = nm;
            }
    }

    float linv[2][4];
    #pragma unroll
    for (int i = 0; i < 2; ++i)
        #pragma unroll
        for (int g = 0; g < 4; ++g) linv[i][g] = 1.0f / l[i][g];

    f32x4 O[2][8];
    #pragma unroll
    for (int i = 0; i < 2; ++i)
        #pragma unroll
        for (int nb = 0; nb < 8; ++nb) O[i][nb] = f32x4{0.f, 0.f, 0.f, 0.f};

    float* abase = atts + (long)bh * 262144;

    // ---- pass 2: att write + O accumulate ----
    for (int kt = 0; kt <= qb; ++kt) {
        __syncthreads();
        const __bf16* ksrc = QK + ((long)(b * 512 + kt * 128)) * 2048 + 1024 + h * 128;
        const __bf16* vsrc = Vt + (long)bh * 65536 + kt * 128;
        for (int c = t; c < 2048; c += 256) {
            const int row = c >> 4, col = (c & 15) * 8;
            *(bf16x8*)&Ks[row * 136 + col] = *(const bf16x8*)(ksrc + (long)row * 2048 + col);
            *(bf16x8*)&Vs[row * 136 + col] = *(const bf16x8*)(vsrc + (long)row * 512 + col);
        }
        __syncthreads();

        f32x4 S[2][8];
        #pragma unroll
        for (int i = 0; i < 2; ++i)
            #pragma unroll
            for (int nb = 0; nb < 8; ++nb) S[i][nb] = f32x4{0.f, 0.f, 0.f, 0.f};
        #pragma unroll
        for (int kp = 0; kp < 4; ++kp) {
            bf16x8 af[2], bv[8];
            #pragma unroll
            for (int i = 0; i < 2; ++i)
                af[i] = *(const bf16x8*)&Qs[(w * 32 + i * 16 + r) * 136 + kp * 32 + q * 8];
            #pragma unroll
            for (int nb = 0; nb < 8; ++nb)
                bv[nb] = *(const bf16x8*)&Ks[(nb * 16 + r) * 136 + kp * 32 + q * 8];
            #pragma unroll
            for (int i = 0; i < 2; ++i)
                #pragma unroll
                for (int nb = 0; nb < 8; ++nb)
                    S[i][nb] = __builtin_amdgcn_mfma_f32_16x16x32_bf16(af[i], bv[nb], S[i][nb], 0, 0, 0);
        }

        #pragma unroll
        for (int i = 0; i < 2; ++i)
            #pragma unroll
            for (int nb = 0; nb < 8; ++nb)
                #pragma unroll
                for (int g = 0; g < 4; ++g) {
                    const int qr = w * 32 + i * 16 + q * 4 + g, kc = nb * 16 + r;
                    float v = S[i][nb][g] * rs;
                    if (kt == qb && kc > qr) v = -1e9f;
                    const float p = __expf(v - m[i][g]) * linv[i][g];
                    abase[(long)(qb * 128 + qr) * 512 + kt * 128 + kc] = p;
                    Ps[qr * 136 + kc] = (__bf16)p;
                }

        #pragma unroll
        for (int kp = 0; kp < 4; ++kp) {
            bf16x8 af[2], bv[8];
            #pragma unroll
            for (int i = 0; i < 2; ++i)
                af[i] = *(const bf16x8*)&Ps[(w * 32 + i * 16 + r) * 136 + kp * 32 + q * 8];
            #pragma unroll
            for (int nb = 0; nb < 8; ++nb)
                bv[nb] = *(const bf16x8*)&Vs[(nb * 16 + r) * 136 + kp * 32 + q * 8];
            #pragma unroll
            for (int i = 0; i < 2; ++i)
                #pragma unroll
                for (int nb = 0; nb < 8; ++nb)
                    O[i][nb] = __builtin_amdgcn_mfma_f32_16x16x32_bf16(af[i], bv[nb], O[i][nb], 0, 0, 0);
        }
    }

    // zero-fill fully-masked upper tiles (exact per reference: exp underflow -> 0)
    for (int kt = qb + 1; kt < 4; ++kt) {
        float4 z4 = {0.f, 0.f, 0.f, 0.f};
        float* zb = abase + (long)(qb * 128) * 512 + kt * 128;
        for (int c = t; c < 4096; c += 256) {
            const int row = c >> 5, col = (c & 31) * 4;
            *(float4*)&zb[(long)row * 512 + col] = z4;
        }
    }

    // write O -> comb
    #pragma unroll
    for (int i = 0; i < 2; ++i)
        #pragma unroll
        for (int nb = 0; nb < 8; ++nb)
            #pragma unroll
            for (int g = 0; g < 4; ++g) {
                const int qr = w * 32 + i * 16 + q * 4 + g;
                comb[((long)(b * 512 + qb * 128 + qr)) * 1024 + h * 128 + nb * 16 + r] =
                    (__bf16)O[i][nb][g];
            }
}

extern "C" void kernel_launch(void* const* d_in, const int* in_sizes, int n_in,
                              void* d_out, int out_size, void* d_ws, size_t ws_size,
                              hipStream_t stream)
{
    const float* tokens = (const float*)d_in[0];
    const float* embedW = (const float*)d_in[2];
    const float* unembW = (const float*)d_in[3];
    const float* wq     = (const float*)d_in[4];
    const float* wk     = (const float*)d_in[5];
    const float* wv     = (const float*)d_in[6];
    const float* wo     = (const float*)d_in[7];

    float* out       = (float*)d_out;
    float* logits_o  = out;                 // [8,512,256]
    float* atts_o    = out + 1048576L;      // [4,64,512,512]
    float* streams_o = atts_o + 67108864L;  // [5,4096,1024]

    __bf16* embedWt   = (__bf16*)d_ws;            // [1024][256]
    __bf16* unembWt   = embedWt + 262144;         // [256][1024]
    __bf16* WtAll     = unembWt + 262144;         // [L][3072][1024]
    __bf16* WotAll    = WtAll + 12582912;         // [L][1024][1024]
    __bf16* tokens_bf = WotAll + 4194304;         // [4096][256]
    __bf16* stream_bf = tokens_bf + 1048576;      // [4096][1024]
    __bf16* QKbuf     = stream_bf + 4194304;      // [4096][2048]
    __bf16* Vt        = QKbuf + 8388608;          // [64][128][512]
    __bf16* comb      = Vt + 4194304;             // [4096][1024]

    const dim3 T(32, 8), G1(256);

    // prep: token convert + all weight transposes (no interdependencies)
    cvt_bf16<<<dim3(1024), G1, 0, stream>>>(tokens, tokens_bf);
    transpose_cvt<<<dim3(32, 8, 1), T, 0, stream>>>(embedW, embedWt, 1024, 256, 0, 1, 0, 0);
    transpose_cvt<<<dim3(8, 32, 1), T, 0, stream>>>(unembW, unembWt, 256, 1024, 0, 1, 0, 0);
    transpose_cvt<<<dim3(4, 32, 32), T, 0, stream>>>(wq, WtAll,           128, 1024, 131072, 8, 3145728, 131072);
    transpose_cvt<<<dim3(4, 32, 32), T, 0, stream>>>(wk, WtAll + 1048576, 128, 1024, 131072, 8, 3145728, 131072);
    transpose_cvt<<<dim3(4, 32, 32), T, 0, stream>>>(wv, WtAll + 2097152, 128, 1024, 131072, 8, 3145728, 131072);
    transpose_cvt<<<dim3(32, 32, 4), T, 0, stream>>>(wo, WotAll, 1024, 1024, 1048576, 1, 1048576, 0);

    // embed: [4096,256] x [256->1024]
    mfma_gemm<<<dim3(8, 32), G1, 0, stream>>>(
        tokens_bf, embedWt, 256, 256, 256,
        streams_o, 1024, stream_bf, 1024, nullptr, nullptr, 0);

    for (int l = 0; l < 4; ++l) {
        float* st  = streams_o + (long)l * 4194304;
        float* stn = st + 4194304;
        float* attl = atts_o + (long)l * 16777216;

        // QKV: [4096,1024] x [1024->3072]; q,k -> QKbuf, v -> Vt (transposed)
        mfma_gemm<<<dim3(24, 32), G1, 0, stream>>>(
            stream_bf, WtAll + (long)l * 3145728, 1024, 1024, 1024,
            nullptr, 0, QKbuf, 2048, Vt, nullptr, 0);

        flash_k<<<dim3(4, 64), G1, 0, stream>>>(QKbuf, Vt, attl, comb);

        // stream_{l+1} = stream_l + comb @ wo
        mfma_gemm<<<dim3(8, 32), G1, 0, stream>>>(
            comb, WotAll + (long)l * 1048576, 1024, 1024, 1024,
            stn, 1024, stream_bf, 1024, nullptr, st, 1024);
    }

    // logits = stream_L @ unembW
    mfma_gemm<<<dim3(2, 32), G1, 0, stream>>>(
        stream_bf, unembWt, 1024, 1024, 1024,
        logits_o, 256, nullptr, 0, nullptr, nullptr, 0);
}